// Round 8
// baseline (208.299 us; speedup 1.0000x reference)
//
#include <hip/hip_runtime.h>
#include <hip/hip_bf16.h>

#define B_  8
#define Q_  32
#define LE_ 128
#define D_  512
#define P_  32
#define A_  128

typedef __attribute__((ext_vector_type(8))) short short8_t;   // 8 bf16 (4 VGPRs)
typedef __attribute__((ext_vector_type(4))) float floatx4_t;  // 4 fp32 acc
typedef float f32x2 __attribute__((ext_vector_type(2)));

typedef const __attribute__((address_space(1))) unsigned int glb_uint;
typedef __attribute__((address_space(3))) unsigned int lds_uint;
#define GLD16(g, s) __builtin_amdgcn_global_load_lds((glb_uint*)(g), (lds_uint*)(s), 16, 0, 0)

// fp32 -> bf16 round-to-nearest-even, raw bits
__device__ __forceinline__ short f2bf(float x) {
    unsigned u = __float_as_uint(x);
    unsigned r = (u + 0x7fffu + ((u >> 16) & 1u)) >> 16;
    return (short)r;
}

// ---------------- K0: convert X fp32 -> Xb bf16 AND XbT bf16 (transposed), W -> Wb
// blocks [0,1024): (bq, d-chunk 128): Xb rows + XbT via LDS transpose.
// blocks [1024,1056): W convert.
#define TP_ 136   // LDS transpose tile row pad (shorts)
__global__ __launch_bounds__(256) void convert_kernel(
    const float* __restrict__ X, const float* __restrict__ W,
    short* __restrict__ Xb, short* __restrict__ XbT, short* __restrict__ Wb) {
    int blk = blockIdx.x;
    int tid = threadIdx.x;
    if (blk >= 1024) {
        size_t base = (size_t)(blk - 1024) * 2048 + tid * 8;
        float4 v0 = ((const float4*)(W + base))[0];
        float4 v1 = ((const float4*)(W + base))[1];
        short8_t s;
        s[0] = f2bf(v0.x); s[1] = f2bf(v0.y); s[2] = f2bf(v0.z); s[3] = f2bf(v0.w);
        s[4] = f2bf(v1.x); s[5] = f2bf(v1.y); s[6] = f2bf(v1.z); s[7] = f2bf(v1.w);
        *(short8_t*)(Wb + base) = s;
        return;
    }
    __shared__ short tile[128 * TP_];   // [d][t], 34.8 KB
    int bq = blk >> 2, d0 = (blk & 3) * 128;
    int tt = tid >> 5, dd = (tid & 31) * 4;
#pragma unroll 4
    for (int pass = 0; pass < 16; ++pass) {
        int t = tt + pass * 8;
        float4 v = *(const float4*)(X + (size_t)(bq * LE_ + t) * D_ + d0 + dd);
        short s0 = f2bf(v.x), s1 = f2bf(v.y), s2 = f2bf(v.z), s3 = f2bf(v.w);
        // Xb row write (8B)
        short* xd = Xb + (size_t)(bq * LE_ + t) * D_ + d0 + dd;
        xd[0] = s0; xd[1] = s1; xd[2] = s2; xd[3] = s3;
        // LDS transposed
        tile[(dd + 0) * TP_ + t] = s0;
        tile[(dd + 1) * TP_ + t] = s1;
        tile[(dd + 2) * TP_ + t] = s2;
        tile[(dd + 3) * TP_ + t] = s3;
    }
    __syncthreads();
    int dr = tid >> 1, th = (tid & 1) * 64;
    short* dst = XbT + ((size_t)(bq * D_) + d0 + dr) * LE_ + th;
#pragma unroll
    for (int i = 0; i < 8; ++i)
        *(short8_t*)(dst + i * 8) = *(const short8_t*)(tile + dr * TP_ + th + i * 8);
}

// ---------------- K1: EW[b,p,a] = exp(2*(s_j[b,p,:]·Ws_w[a,:] + Ws_b[a])) -------
__global__ __launch_bounds__(128) void ws_kernel(
    const float* __restrict__ s_j, const float* __restrict__ Ws_w,
    const float* __restrict__ Ws_b, float* __restrict__ ws) {
    __shared__ float s_row[D_];
    int bp = blockIdx.x;
    const float* src = s_j + (size_t)bp * D_;
    for (int i = threadIdx.x; i < D_; i += 128) s_row[i] = src[i];
    __syncthreads();
    int a = threadIdx.x;
    const float4* w4 = (const float4*)(Ws_w + (size_t)a * D_);
    const float4* s4 = (const float4*)s_row;
    float acc = 0.0f;
#pragma unroll 8
    for (int i = 0; i < D_ / 4; ++i) {
        float4 w = w4[i];
        float4 s = s4[i];
        acc += w.x * s.x + w.y * s.y + w.z * s.z + w.w * s.w;
    }
    ws[bp * A_ + a] = __expf(2.0f * (acc + Ws_b[a]));
}

// ---------------- K2: EU = exp(2*uh); bf16 MFMA, global_load_lds staging --------
__global__ __launch_bounds__(256, 2) void uh_mfma_kernel(
    const short* __restrict__ Xb, const short* __restrict__ Wb,
    float* __restrict__ uh) {
    __shared__ short As[64 * 64];    // 8 KB, chunk-swizzled
    __shared__ short Bs[128 * 64];   // 16 KB
    int mblk = blockIdx.x * 64;
    int tid = threadIdx.x;
    int wave = tid >> 6, lane = tid & 63;
    int qd = lane >> 4, lr = lane & 15;
    int mh = wave >> 1, nh = wave & 1;
    int axor = lr & 7;

    int cA = lane & 7;
    int rowA0 = wave * 16 + (lane >> 3);
    int rowB0 = wave * 32 + (lane >> 3);

    floatx4_t acc[2][4];
#pragma unroll
    for (int i = 0; i < 2; ++i)
#pragma unroll
        for (int j = 0; j < 4; ++j) acc[i][j] = (floatx4_t){0.f, 0.f, 0.f, 0.f};

    for (int kt = 0; kt < 8; ++kt) {
        int k0 = kt * 64;
        if (kt) __syncthreads();
#pragma unroll
        for (int u = 0; u < 2; ++u) {
            int m = rowA0 + u * 8;
            const short* g = Xb + (size_t)(mblk + m) * D_ + k0 + ((cA ^ (m & 7)) * 8);
            GLD16(g, As + (wave * 2 + u) * 512);
        }
#pragma unroll
        for (int u = 0; u < 4; ++u) {
            int n = rowB0 + u * 8;
            const short* g = Wb + (size_t)n * D_ + k0 + ((cA ^ (n & 7)) * 8);
            GLD16(g, Bs + (wave * 4 + u) * 512);
        }
        __syncthreads();
#pragma unroll
        for (int ks = 0; ks < 2; ++ks) {
            int cr = (ks * 4 + qd) ^ axor;
            short8_t af[2], bfr[4];
#pragma unroll
            for (int i = 0; i < 2; ++i)
                af[i] = *(const short8_t*)(As + (mh * 32 + i * 16 + lr) * 64 + cr * 8);
#pragma unroll
            for (int j = 0; j < 4; ++j)
                bfr[j] = *(const short8_t*)(Bs + (nh * 64 + j * 16 + lr) * 64 + cr * 8);
#pragma unroll
            for (int i = 0; i < 2; ++i)
#pragma unroll
                for (int j = 0; j < 4; ++j)
                    acc[i][j] = __builtin_amdgcn_mfma_f32_16x16x32_bf16(af[i], bfr[j], acc[i][j], 0, 0, 0);
        }
    }
#pragma unroll
    for (int i = 0; i < 2; ++i) {
#pragma unroll
        for (int j = 0; j < 4; ++j) {
            int mg = mblk + mh * 32 + i * 16 + qd * 4;
            int ng = nh * 64 + j * 16 + lr;
            float* dst = uh + (size_t)mg * A_ + ng;
#pragma unroll
            for (int r = 0; r < 4; ++r)
                dst[(size_t)r * A_] = __expf(2.0f * acc[i][j][r]);
        }
    }
}

// -------- K3: Eeb[b,q,p,t] = bf16(mask ? exp(-sum_a 2*v[a]/(1+EU*EW)) : 0) ------
//            + atomic per-(b,p) partial sums (stats kernel folded in)
__global__ __launch_bounds__(256) void score_kernel(
    const float* __restrict__ EU, const float* __restrict__ EW,
    const float* __restrict__ v_w, const int* __restrict__ exp_mask,
    short* __restrict__ Eeb, float* __restrict__ sums) {
    __shared__ float eu_t[32][132];
    __shared__ float ew_t[32][128];
    __shared__ float n2v[128];
    int blk = blockIdx.x;
    int bq = blk >> 2, tc = blk & 3;
    int b = bq >> 5;
    int t0 = tc * 32;
    int tid = threadIdx.x;

#pragma unroll
    for (int i = 0; i < 4; ++i) {
        int f = tid + i * 256;
        int t = f >> 5, a4 = f & 31;
        float4 v = *(const float4*)(EU + (size_t)(bq * LE_ + t0 + t) * A_ + a4 * 4);
        *(float4*)&eu_t[t][a4 * 4] = v;
    }
#pragma unroll
    for (int i = 0; i < 4; ++i) {
        int f = tid + i * 256;
        int p = f >> 5, a4 = f & 31;
        *(float4*)&ew_t[p][a4 * 4] =
            *(const float4*)(EW + (size_t)(b * P_ + p) * A_ + a4 * 4);
    }
    if (tid < 32) {
        float4 v = *(const float4*)(v_w + tid * 4);
        v.x *= -2.0f; v.y *= -2.0f; v.z *= -2.0f; v.w *= -2.0f;
        *(float4*)&n2v[tid * 4] = v;
    }
    __syncthreads();

    int t = tid & 31, pb = tid >> 5;
    int mask = exp_mask[bq * LE_ + t0 + t];
    float acc[4] = {0.f, 0.f, 0.f, 0.f};
    for (int a4 = 0; a4 < 32; ++a4) {
        float4 u = *(const float4*)&eu_t[t][a4 * 4];
        float4 vv = *(const float4*)&n2v[a4 * 4];
#pragma unroll
        for (int i = 0; i < 4; ++i) {
            float4 w = *(const float4*)&ew_t[pb + i * 8][a4 * 4];
            acc[i] = fmaf(vv.x, __builtin_amdgcn_rcpf(fmaf(u.x, w.x, 1.0f)), acc[i]);
            acc[i] = fmaf(vv.y, __builtin_amdgcn_rcpf(fmaf(u.y, w.y, 1.0f)), acc[i]);
            acc[i] = fmaf(vv.z, __builtin_amdgcn_rcpf(fmaf(u.z, w.z, 1.0f)), acc[i]);
            acc[i] = fmaf(vv.w, __builtin_amdgcn_rcpf(fmaf(u.w, w.w, 1.0f)), acc[i]);
        }
    }
#pragma unroll
    for (int i = 0; i < 4; ++i) {
        int p = pb + i * 8;
        float ev = mask ? __expf(acc[i]) : 0.0f;
        Eeb[(size_t)(bq * P_ + p) * LE_ + t0 + t] = f2bf(ev);
        float s = ev;
        s += __shfl_down(s, 16, 32);
        s += __shfl_down(s, 8, 32);
        s += __shfl_down(s, 4, 32);
        s += __shfl_down(s, 2, 32);
        s += __shfl_down(s, 1, 32);
        if (t == 0) atomicAdd(&sums[b * P_ + p], s);
    }
}

// -------- K5: out[p][d] = rinv[p] * sum_t w[p][t] * XbT[d][t]  via MFMA ---------
// grid: bq*4 + dq; 256 thr = 4 waves; wave: 32 d (2 n-tiles), 2 m-tiles, K=128.
#define WP_ 140
__global__ __launch_bounds__(256) void out_mfma_kernel(
    const short* __restrict__ Eeb, const float* __restrict__ sums,
    const short* __restrict__ XbT, const int* __restrict__ req_mask,
    float* __restrict__ out) {
    __shared__ short wlds[32 * WP_];   // [p][t] bf16, padded
    __shared__ float rinv_s[32];
    int bq = blockIdx.x >> 2, dq = blockIdx.x & 3;
    int b = bq >> 5;
    int tid = threadIdx.x;

#pragma unroll
    for (int i = 0; i < 2; ++i) {
        int c = tid + i * 256;          // 512 chunks of 8
        int p = c >> 4, off = (c & 15) * 8;
        short8_t v = *(const short8_t*)(Eeb + ((size_t)bq * P_ + p) * LE_ + off);
        *(short8_t*)(wlds + p * WP_ + off) = v;
    }
    if (tid < 32) {
        int bp = b * P_ + tid;
        float s = sums[bp];
        rinv_s[tid] = req_mask[bp] ? __fdividef(1.0f, s) : 0.0f;
    }
    __syncthreads();

    int wave = tid >> 6, lane = tid & 63;
    int qd = lane >> 4, lr = lane & 15;
    int n0 = dq * 128 + wave * 32;

    short8_t af[2][4];
#pragma unroll
    for (int i = 0; i < 2; ++i)
#pragma unroll
        for (int ks = 0; ks < 4; ++ks)
            af[i][ks] = *(const short8_t*)(wlds + (i * 16 + lr) * WP_ + ks * 32 + qd * 8);

    floatx4_t acc[2][2];
#pragma unroll
    for (int i = 0; i < 2; ++i)
#pragma unroll
        for (int j = 0; j < 2; ++j) acc[i][j] = (floatx4_t){0.f, 0.f, 0.f, 0.f};

    const short* Bbase = XbT + (size_t)bq * D_ * LE_;
#pragma unroll
    for (int ks = 0; ks < 4; ++ks) {
#pragma unroll
        for (int j = 0; j < 2; ++j) {
            short8_t bfr = *(const short8_t*)(Bbase + (size_t)(n0 + j * 16 + lr) * LE_ + ks * 32 + qd * 8);
            acc[0][j] = __builtin_amdgcn_mfma_f32_16x16x32_bf16(af[0][ks], bfr, acc[0][j], 0, 0, 0);
            acc[1][j] = __builtin_amdgcn_mfma_f32_16x16x32_bf16(af[1][ks], bfr, acc[1][j], 0, 0, 0);
        }
    }
    // C/D: col = lane&15 (d), row = qd*4+r (p)
#pragma unroll
    for (int i = 0; i < 2; ++i) {
#pragma unroll
        for (int r = 0; r < 4; ++r) {
            int p = i * 16 + qd * 4 + r;
            float rm = rinv_s[p];
#pragma unroll
            for (int j = 0; j < 2; ++j) {
                int d = n0 + j * 16 + lr;
                out[((size_t)bq * P_ + p) * D_ + d] = acc[i][j][r] * rm;
            }
        }
    }
}

extern "C" void kernel_launch(void* const* d_in, const int* in_sizes, int n_in,
                              void* d_out, int out_size, void* d_ws, size_t ws_size,
                              hipStream_t stream) {
    const float* exp_tokens = (const float*)d_in[0];
    const int*   exp_mask   = (const int*)d_in[1];
    const float* s_j        = (const float*)d_in[2];
    const int*   req_mask   = (const int*)d_in[3];
    const float* Ws_w       = (const float*)d_in[4];
    const float* Ws_b       = (const float*)d_in[5];
    const float* U_w        = (const float*)d_in[6];
    const float* v_w        = (const float*)d_in[7];
    float* out = (float*)d_out;

    float* EW   = (float*)d_ws;                           // 32768
    float* EU   = EW + B_ * P_ * A_;                      // 4194304
    float* sums = EU + (size_t)B_ * Q_ * LE_ * A_;        // 256
    short* Eeb  = (short*)(sums + 256);                   // 1048576 shorts
    short* Xb   = Eeb + (size_t)B_ * Q_ * P_ * LE_;       // 16.7M shorts
    short* XbT  = Xb + (size_t)B_ * Q_ * LE_ * D_;        // 16.7M shorts
    short* Wb   = XbT + (size_t)B_ * Q_ * LE_ * D_;       // 64K shorts

    hipMemsetAsync(sums, 0, B_ * P_ * sizeof(float), stream);
    convert_kernel<<<dim3(1024 + 32), dim3(256), 0, stream>>>(exp_tokens, U_w, Xb, XbT, Wb);
    ws_kernel<<<dim3(B_ * P_), dim3(128), 0, stream>>>(s_j, Ws_w, Ws_b, EW);
    uh_mfma_kernel<<<dim3(B_ * Q_ * LE_ / 64), dim3(256), 0, stream>>>(Xb, Wb, EU);
    score_kernel<<<dim3(B_ * Q_ * 4), dim3(256), 0, stream>>>(EU, EW, v_w, exp_mask, Eeb, sums);
    out_mfma_kernel<<<dim3(B_ * Q_ * 4), dim3(256), 0, stream>>>(Eeb, sums, XbT, req_mask, out);
}

// Round 9
// 169.627 us; speedup vs baseline: 1.2280x; 1.2280x over previous
//
#include <hip/hip_runtime.h>
#include <hip/hip_bf16.h>

#define B_  8
#define Q_  32
#define LE_ 128
#define D_  512
#define P_  32
#define A_  128

typedef __attribute__((ext_vector_type(8))) short short8_t;   // 8 bf16 (4 VGPRs)
typedef __attribute__((ext_vector_type(4))) float floatx4_t;  // 4 fp32 acc

typedef const __attribute__((address_space(1))) unsigned int glb_uint;
typedef __attribute__((address_space(3))) unsigned int lds_uint;
#define GLD16(g, s) __builtin_amdgcn_global_load_lds((glb_uint*)(g), (lds_uint*)(s), 16, 0, 0)

// fp32 -> bf16 round-to-nearest-even, raw bits
__device__ __forceinline__ short f2bf(float x) {
    unsigned u = __float_as_uint(x);
    unsigned r = (u + 0x7fffu + ((u >> 16) & 1u)) >> 16;
    return (short)r;
}
__device__ __forceinline__ float bf2f(short s) {
    return __uint_as_float(((unsigned)(unsigned short)s) << 16);
}

// ---------------- K0: convert X (16.7M) and W (64K) fp32 -> bf16 -----------------
__global__ __launch_bounds__(256) void convert_kernel(
    const float* __restrict__ X, const float* __restrict__ W,
    short* __restrict__ Xb, short* __restrict__ Wb) {
    int b = blockIdx.x;
    const float* src;
    short* dst;
    size_t base;
    if (b < 8192) {
        base = ((size_t)b * 256 + threadIdx.x) * 8;
        src = X + base; dst = Xb + base;
    } else {
        base = ((size_t)(b - 8192) * 256 + threadIdx.x) * 8;
        src = W + base; dst = Wb + base;
    }
    float4 v0 = ((const float4*)src)[0];
    float4 v1 = ((const float4*)src)[1];
    short8_t s;
    s[0] = f2bf(v0.x); s[1] = f2bf(v0.y); s[2] = f2bf(v0.z); s[3] = f2bf(v0.w);
    s[4] = f2bf(v1.x); s[5] = f2bf(v1.y); s[6] = f2bf(v1.z); s[7] = f2bf(v1.w);
    *(short8_t*)dst = s;
}

// ---------------- K1: EW[b,p,a] = exp(2*(s_j[b,p,:]·Ws_w[a,:] + Ws_b[a])) -------
__global__ __launch_bounds__(128) void ws_kernel(
    const float* __restrict__ s_j, const float* __restrict__ Ws_w,
    const float* __restrict__ Ws_b, float* __restrict__ ws) {
    __shared__ float s_row[D_];
    int bp = blockIdx.x;
    const float* src = s_j + (size_t)bp * D_;
    for (int i = threadIdx.x; i < D_; i += 128) s_row[i] = src[i];
    __syncthreads();
    int a = threadIdx.x;
    const float4* w4 = (const float4*)(Ws_w + (size_t)a * D_);
    const float4* s4 = (const float4*)s_row;
    float acc = 0.0f;
#pragma unroll 8
    for (int i = 0; i < D_ / 4; ++i) {
        float4 w = w4[i];
        float4 s = s4[i];
        acc += w.x * s.x + w.y * s.y + w.z * s.z + w.w * s.w;
    }
    ws[bp * A_ + a] = __expf(2.0f * (acc + Ws_b[a]));
}

// ---------------- K2: FUSED per-bq kernel ----------------------------------------
// Phase 1: uh[t=128][a=128] = Xb[bq]·Wb^T (K=512) via MFMA + GLD16
// Phase 2: EU = bf16(exp(2 uh)) -> LDS; load EW, n2v, mask
// Phase 3: score -> w[p][t] = bf16(exp(-sum_a 2 v_a /(1+EU·EW))) (mask->0)
// Sums:    per-p sum of w -> global atomic gsums[b,p]
// Phase 4: out_un[p][d] = sum_t w[p][t]·Xb[t][d] via MFMA (B staged by LDS transpose)
#define EUP_ 136   // EU / pvB row stride (shorts)
#define EWP_ 132   // EW row stride (floats)
#define WPP_ 136   // w_lds row stride (shorts)

__global__ __launch_bounds__(512, 1) void fused_kernel(
    const short* __restrict__ Xb, const short* __restrict__ Wb,
    const float* __restrict__ EW, const float* __restrict__ v_w,
    const int* __restrict__ exp_mask, float* __restrict__ gsums,
    float* __restrict__ out) {
    __shared__ short uA[128 * EUP_];   // 34816 B union: {As+Bs staging} / EU / pvB
    __shared__ float ew_s[32 * EWP_];  // 16896 B
    __shared__ short w_s[32 * WPP_];   // 8704 B
    __shared__ float n2v[128];
    __shared__ int   mask_s[128];

    int bq = blockIdx.x;
    int b  = bq >> 5;
    int tid = threadIdx.x;
    int wave = tid >> 6, lane = tid & 63;
    int qd = lane >> 4, lr = lane & 15;

    short* As = uA;            // 8192 shorts (16 KB)
    short* Bs = uA + 8192;     // 8192 shorts (16 KB)

    // ---- phase 1: uh GEMM ----
    int m0 = (wave >> 1) * 32, n0 = (wave & 1) * 64;
    int cA = lane & 7;
    int row0 = wave * 16 + (lane >> 3);

    floatx4_t acc[2][4];
#pragma unroll
    for (int i = 0; i < 2; ++i)
#pragma unroll
        for (int j = 0; j < 4; ++j) acc[i][j] = (floatx4_t){0.f, 0.f, 0.f, 0.f};

    for (int kt = 0; kt < 8; ++kt) {
        int k0 = kt * 64;
        __syncthreads();
#pragma unroll
        for (int u = 0; u < 2; ++u) {
            int m = row0 + u * 8;
            GLD16(Xb + (size_t)(bq * 128 + m) * D_ + k0 + ((cA ^ (m & 7)) * 8),
                  As + (wave * 2 + u) * 512);
        }
#pragma unroll
        for (int u = 0; u < 2; ++u) {
            int n = row0 + u * 8;
            GLD16(Wb + (size_t)n * D_ + k0 + ((cA ^ (n & 7)) * 8),
                  Bs + (wave * 2 + u) * 512);
        }
        __syncthreads();
#pragma unroll
        for (int ks = 0; ks < 2; ++ks) {
            int cr = (ks * 4 + qd) ^ (lr & 7);
            short8_t af[2], bfr[4];
#pragma unroll
            for (int i = 0; i < 2; ++i)
                af[i] = *(const short8_t*)(As + (m0 + i * 16 + lr) * 64 + cr * 8);
#pragma unroll
            for (int j = 0; j < 4; ++j)
                bfr[j] = *(const short8_t*)(Bs + (n0 + j * 16 + lr) * 64 + cr * 8);
#pragma unroll
            for (int i = 0; i < 2; ++i)
#pragma unroll
                for (int j = 0; j < 4; ++j)
                    acc[i][j] = __builtin_amdgcn_mfma_f32_16x16x32_bf16(af[i], bfr[j], acc[i][j], 0, 0, 0);
        }
    }
    __syncthreads();   // staging LDS dead -> becomes EU

    // ---- phase 2: EU to LDS (bf16), load EW / n2v / mask ----
#pragma unroll
    for (int i = 0; i < 2; ++i)
#pragma unroll
        for (int j = 0; j < 4; ++j)
#pragma unroll
            for (int r = 0; r < 4; ++r) {
                int t = m0 + i * 16 + qd * 4 + r;
                int a = n0 + j * 16 + lr;
                uA[t * EUP_ + a] = f2bf(__expf(2.0f * acc[i][j][r]));
            }
#pragma unroll
    for (int u = 0; u < 2; ++u) {
        int c = tid * 2 + u;              // 1024 float4 = 4096 floats
        int p = c >> 5, seg = c & 31;
        *(float4*)&ew_s[p * EWP_ + seg * 4] =
            *(const float4*)&EW[(size_t)(b * P_ + p) * A_ + seg * 4];
    }
    if (tid < 32) {
        float4 v = *(const float4*)(v_w + tid * 4);
        v.x *= -2.0f; v.y *= -2.0f; v.z *= -2.0f; v.w *= -2.0f;
        *(float4*)&n2v[tid * 4] = v;
    }
    if (tid < 128) mask_s[tid] = exp_mask[bq * LE_ + tid];
    __syncthreads();

    // ---- phase 3: score. thread = (t = tid&127, pg = tid>>7); 8 p per thread ----
    {
        int t = tid & 127, pg = tid >> 7;
        float acc8[8];
#pragma unroll
        for (int j = 0; j < 8; ++j) acc8[j] = 0.0f;
        for (int a8 = 0; a8 < 16; ++a8) {
            short8_t e8 = *(const short8_t*)&uA[t * EUP_ + a8 * 8];
            float eu[8];
#pragma unroll
            for (int k = 0; k < 8; ++k) eu[k] = bf2f(e8[k]);
            float4 nv0 = *(const float4*)&n2v[a8 * 8];
            float4 nv1 = *(const float4*)&n2v[a8 * 8 + 4];
            float nv[8] = {nv0.x, nv0.y, nv0.z, nv0.w, nv1.x, nv1.y, nv1.z, nv1.w};
#pragma unroll
            for (int j = 0; j < 8; ++j) {
                int p = pg * 8 + j;
                float4 w0 = *(const float4*)&ew_s[p * EWP_ + a8 * 8];
                float4 w1 = *(const float4*)&ew_s[p * EWP_ + a8 * 8 + 4];
                float ww[8] = {w0.x, w0.y, w0.z, w0.w, w1.x, w1.y, w1.z, w1.w};
#pragma unroll
                for (int k = 0; k < 8; ++k)
                    acc8[j] = fmaf(nv[k], __builtin_amdgcn_rcpf(fmaf(eu[k], ww[k], 1.0f)), acc8[j]);
            }
        }
        int mk = mask_s[t];
#pragma unroll
        for (int j = 0; j < 8; ++j) {
            float ee = mk ? __expf(acc8[j]) : 0.0f;
            w_s[(pg * 8 + j) * WPP_ + t] = f2bf(ee);
        }
    }
    __syncthreads();   // w_s complete; EU dead -> uA becomes pvB

    // ---- sums: per-p reduce of w_s, one global atomic per p ----
    if (tid < 256) {
        int p = tid >> 3, seg = tid & 7;
        const short* src = w_s + p * WPP_ + seg * 16;
        float s = 0.0f;
#pragma unroll
        for (int k = 0; k < 16; ++k) s += bf2f(src[k]);
        s += __shfl_xor(s, 1);
        s += __shfl_xor(s, 2);
        s += __shfl_xor(s, 4);
        if (seg == 0) atomicAdd(&gsums[b * P_ + p], s);
    }

    // ---- phase 4: PV.  out_un[p][d] = sum_t w[p][t] * Xb[t][d] ----
    short8_t afv[2][4];
#pragma unroll
    for (int i = 0; i < 2; ++i)
#pragma unroll
        for (int ks = 0; ks < 4; ++ks)
            afv[i][ks] = *(const short8_t*)&w_s[(i * 16 + lr) * WPP_ + ks * 32 + qd * 8];

    int tt = tid >> 2, dseg = (tid & 3) * 32;
    for (int chunk = 0; chunk < 4; ++chunk) {
        int d0 = chunk * 128;
        __syncthreads();   // prior chunk's pvB reads done
        // stage: transpose Xb[t][d0..d0+128) -> pvB[d_local][t]
        const short8_t* g = (const short8_t*)(Xb + (size_t)(bq * 128 + tt) * D_ + d0 + dseg);
        short8_t xs0 = g[0], xs1 = g[1], xs2 = g[2], xs3 = g[3];
#pragma unroll
        for (int e = 0; e < 8; ++e) {
            uA[(dseg + 0 + e) * EUP_ + tt]  = xs0[e];
            uA[(dseg + 8 + e) * EUP_ + tt]  = xs1[e];
            uA[(dseg + 16 + e) * EUP_ + tt] = xs2[e];
            uA[(dseg + 24 + e) * EUP_ + tt] = xs3[e];
        }
        __syncthreads();
        floatx4_t accp[2];
        accp[0] = (floatx4_t){0.f, 0.f, 0.f, 0.f};
        accp[1] = (floatx4_t){0.f, 0.f, 0.f, 0.f};
#pragma unroll
        for (int ks = 0; ks < 4; ++ks) {
            short8_t bfr = *(const short8_t*)&uA[(wave * 16 + lr) * EUP_ + ks * 32 + qd * 8];
            accp[0] = __builtin_amdgcn_mfma_f32_16x16x32_bf16(afv[0][ks], bfr, accp[0], 0, 0, 0);
            accp[1] = __builtin_amdgcn_mfma_f32_16x16x32_bf16(afv[1][ks], bfr, accp[1], 0, 0, 0);
        }
        // C/D: col = lane&15 (d), row = qd*4+r (p)
#pragma unroll
        for (int i = 0; i < 2; ++i)
#pragma unroll
            for (int r = 0; r < 4; ++r) {
                int p = i * 16 + qd * 4 + r;
                out[((size_t)bq * P_ + p) * D_ + d0 + wave * 16 + lr] = accp[i][r];
            }
    }
}

// ---------------- K3: normalize: out[bq,p,:] *= req_mask/gsums -------------------
__global__ __launch_bounds__(256) void norm_kernel(
    float* __restrict__ out, const float* __restrict__ gsums,
    const int* __restrict__ req_mask) {
    int bqp = blockIdx.x;            // 8192 = bq*32 + p
    int p = bqp & 31;
    int b = bqp >> 10;               // bq = bqp>>5, b = bq>>5
    int bp = b * P_ + p;
    float s = gsums[bp];
    float rm = req_mask[bp] ? __fdividef(1.0f, s) : 0.0f;
    float2* o = (float2*)(out + (size_t)bqp * D_);
    float2 v = o[threadIdx.x];
    v.x *= rm; v.y *= rm;
    o[threadIdx.x] = v;
}

extern "C" void kernel_launch(void* const* d_in, const int* in_sizes, int n_in,
                              void* d_out, int out_size, void* d_ws, size_t ws_size,
                              hipStream_t stream) {
    const float* exp_tokens = (const float*)d_in[0];
    const int*   exp_mask   = (const int*)d_in[1];
    const float* s_j        = (const float*)d_in[2];
    const int*   req_mask   = (const int*)d_in[3];
    const float* Ws_w       = (const float*)d_in[4];
    const float* Ws_b       = (const float*)d_in[5];
    const float* U_w        = (const float*)d_in[6];
    const float* v_w        = (const float*)d_in[7];
    float* out = (float*)d_out;

    float* EW    = (float*)d_ws;                          // 32768 floats
    float* gsums = EW + B_ * P_ * A_;                     // 256 floats
    short* Xb    = (short*)(gsums + 256);                 // 16.7M shorts
    short* Wb    = Xb + (size_t)B_ * Q_ * LE_ * D_;       // 64K shorts

    hipMemsetAsync(gsums, 0, B_ * P_ * sizeof(float), stream);
    convert_kernel<<<dim3(8192 + 32), dim3(256), 0, stream>>>(exp_tokens, U_w, Xb, Wb);
    ws_kernel<<<dim3(B_ * P_), dim3(128), 0, stream>>>(s_j, Ws_w, Ws_b, EW);
    fused_kernel<<<dim3(B_ * Q_), dim3(512), 0, stream>>>(Xb, Wb, EW, v_w, exp_mask, gsums, out);
    norm_kernel<<<dim3(B_ * Q_ * P_), dim3(256), 0, stream>>>(out, gsums, req_mask);
}